// Round 5
// baseline (58240.717 us; speedup 1.0000x reference)
//
#include <hip/hip_runtime.h>

#define T_ 1000

__device__ __forceinline__ float sigf(float x) { return 1.0f / (1.0f + __expf(-x)); }
__device__ __forceinline__ float tanh_fast(float x) { return 1.0f - 2.0f / (1.0f + __expf(2.0f * x)); }
__device__ __forceinline__ float dot4(float4 a, float4 b) {
  return a.x * b.x + a.y * b.y + a.z * b.z + a.w * b.w;
}
__device__ __forceinline__ unsigned short f2bf(float f) {
  unsigned u = __float_as_uint(f);
  u = (u + 0x7fffu + ((u >> 16) & 1u)) >> 16;  // RNE
  return (unsigned short)u;
}
__device__ __forceinline__ float bf2f(unsigned short h) {
  return __uint_as_float(((unsigned)h) << 16);
}
__device__ __forceinline__ float4 bf4_to_f4(ushort4 u) {
  float4 r;
  r.x = bf2f(u.x); r.y = bf2f(u.y); r.z = bf2f(u.z); r.w = bf2f(u.w);
  return r;
}

__global__ void bail_kernel(float* out, int n) {
  for (int i = threadIdx.x; i < n; i += 256) out[i] = 0.0f;
}

// ---------------- Layer-0 recurrence with fused LayerNorm, 1 block per (row,dir) ----------------
// thread (j=tid&127, p=tid>>7): 4 gates of unit j over k-quarter p.
// Wave 2 (p==1, j<64): raw-x group-prefetch (8 steps) + LayerNorm (ahead-by-1).
// Wave-pair p==3: bulk h-store from an 8-step LDS ring once per group.
__global__ __launch_bounds__(512, 2) void rec0_kernel(
    const float* __restrict__ x,
    const float* __restrict__ ln_g, const float* __restrict__ ln_b,
    const float* __restrict__ Wih_f, const float* __restrict__ Whh_f,
    const float* __restrict__ bih_f, const float* __restrict__ bhh_f,
    const float* __restrict__ Wih_b, const float* __restrict__ Whh_b,
    const float* __restrict__ bih_b, const float* __restrict__ bhh_b,
    float* __restrict__ h0) {
  const int tid = threadIdx.x;
  const int j = tid & 127;
  const int p = tid >> 7;
  const int brow = blockIdx.x & 127;
  const int dir = blockIdx.x >> 7;
  const float* __restrict__ Wih = dir ? Wih_b : Wih_f;
  const float* __restrict__ Whh = dir ? Whh_b : Whh_f;
  const float* __restrict__ bih = dir ? bih_b : bih_f;
  const float* __restrict__ bhh = dir ? bhh_b : bhh_f;

  float4 wh[4][8];
  float4 wi[4][3];
#pragma unroll
  for (int g = 0; g < 4; ++g) {
    const int row = g * 128 + j;
    const float4* wr = (const float4*)(Whh + row * 128 + p * 32);
#pragma unroll
    for (int f = 0; f < 8; ++f) wh[g][f] = wr[f];
    const float* xr_ = Wih + row * 40;
#pragma unroll
    for (int f = 0; f < 3; ++f) {
      const int k0 = p * 12 + f * 4;
      float4 tv;
      tv.x = (k0 + 0 < 40) ? xr_[k0 + 0] : 0.0f;
      tv.y = (k0 + 1 < 40) ? xr_[k0 + 1] : 0.0f;
      tv.z = (k0 + 2 < 40) ? xr_[k0 + 2] : 0.0f;
      tv.w = (k0 + 3 < 40) ? xr_[k0 + 3] : 0.0f;
      wi[g][f] = tv;
    }
  }
  const float bias = bih[p * 128 + j] + bhh[p * 128 + j];
  const float b0 = (p == 0) ? bias : 0.0f;
  const float b1 = (p == 1) ? bias : 0.0f;
  const float b2 = (p == 2) ? bias : 0.0f;
  const float b3 = (p == 3) ? bias : 0.0f;

  __shared__ float4 h4[32];      // h state, 128 f
  __shared__ float4 x4[12];      // normalized x row padded to 48 f
  __shared__ float4 part4[384];  // partials from p=1..3
  __shared__ float hring[8][128];

  float gj = 0.0f, bj = 0.0f;
  if (p == 1 && j < 40) { gj = ln_g[j]; bj = ln_b[j]; }

  if (tid < 32) h4[tid] = make_float4(0.f, 0.f, 0.f, 0.f);
  if (tid >= 40 && tid < 48) ((float*)x4)[tid] = 0.0f;  // pad tail
  __syncthreads();

  const long xbase = (long)brow * T_ * 40;
  float xr[8];  // raw x rows for steps (group*8 + u + 1)
  if (p == 1 && j < 64) {
    const long tA = dir ? (T_ - 1) : 0;
    float v = (j < 40) ? x[xbase + tA * 40 + j] : 0.0f;
    float s1 = v, s2 = v * v;
#pragma unroll
    for (int m = 32; m; m >>= 1) {
      s1 += __shfl_xor(s1, m, 64);
      s2 += __shfl_xor(s2, m, 64);
    }
    const float mu = s1 * (1.0f / 40.0f);
    const float var = s2 * (1.0f / 40.0f) - mu * mu;
    const float rs = rsqrtf(var + 1e-5f);
    if (j < 40) ((float*)x4)[j] = (v - mu) * rs * gj + bj;
#pragma unroll
    for (int v8 = 0; v8 < 8; ++v8) {
      const int tr = 1 + v8;
      xr[v8] = 0.0f;
      if (j < 40 && tr < T_) {
        const long tt = dir ? (T_ - 1 - tr) : tr;
        xr[v8] = x[xbase + tt * 40 + j];
      }
    }
  }
  float c = 0.0f;
  __syncthreads();

  const long hbase = (long)brow * T_ * 256;
  for (int sb = 0; sb < 125; ++sb) {
#pragma unroll
    for (int u = 0; u < 8; ++u) {
      const int t = sb * 8 + u;
      float a0 = b0, a1 = b1, a2 = b2, a3 = b3;
#pragma unroll
      for (int f = 0; f < 3; ++f) {
        const float4 xv = x4[p * 3 + f];
        a0 += dot4(xv, wi[0][f]);
        a1 += dot4(xv, wi[1][f]);
        a2 += dot4(xv, wi[2][f]);
        a3 += dot4(xv, wi[3][f]);
      }
#pragma unroll
      for (int f = 0; f < 8; ++f) {
        const float4 hv = h4[p * 8 + f];
        a0 += dot4(hv, wh[0][f]);
        a1 += dot4(hv, wh[1][f]);
        a2 += dot4(hv, wh[2][f]);
        a3 += dot4(hv, wh[3][f]);
      }
      if (p) part4[(p - 1) * 128 + j] = make_float4(a0, a1, a2, a3);
      __syncthreads();  // bar1
      if (!p) {
        const float4 q0 = part4[j], q1 = part4[128 + j], q2 = part4[256 + j];
        a0 += q0.x + q1.x + q2.x;
        a1 += q0.y + q1.y + q2.y;
        a2 += q0.z + q1.z + q2.z;
        a3 += q0.w + q1.w + q2.w;
        const float ig = sigf(a0);
        const float fg = sigf(a1);
        const float gg = tanh_fast(a2);
        const float og = sigf(a3);
        c = fg * c + ig * gg;
        const float hv = og * tanh_fast(c);
        ((float*)h4)[j] = hv;
        hring[u][j] = hv;
      } else if (p == 1 && j < 64) {
        if (t + 1 < T_) {  // LN row t+1 from xr[u]
          float v = xr[u];
          float s1 = v, s2 = v * v;
#pragma unroll
          for (int m = 32; m; m >>= 1) {
            s1 += __shfl_xor(s1, m, 64);
            s2 += __shfl_xor(s2, m, 64);
          }
          const float mu = s1 * (1.0f / 40.0f);
          const float var = s2 * (1.0f / 40.0f) - mu * mu;
          const float rs = rsqrtf(var + 1e-5f);
          if (j < 40) ((float*)x4)[j] = (v - mu) * rs * gj + bj;
        }
      }
      __syncthreads();  // bar2
      if (u == 7) {
        if (p == 3) {  // bulk h-store, drained at next bar1 (amortized 8x)
#pragma unroll
          for (int v = 0; v < 8; ++v) {
            const int ts = sb * 8 + v;
            const int te = dir ? (T_ - 1 - ts) : ts;
            h0[hbase + (long)te * 256 + dir * 128 + j] = hring[v][j];
          }
        } else if (p == 1 && j < 64) {  // refill raw-x group (rows t+2 .. t+9)
#pragma unroll
          for (int v = 0; v < 8; ++v) {
            const int tr = sb * 8 + 9 + v;
            xr[v] = 0.0f;
            if (j < 40 && tr < T_) {
              const long tt = dir ? (T_ - 1 - tr) : tr;
              xr[v] = x[xbase + tt * 40 + j];
            }
          }
        }
      }
    }
  }
}

// ---------------- Layer-1 recurrence, time-chunked; group-8 xw prefetch; bulk bf16 h-store ----------------
__global__ __launch_bounds__(512, 2) void rec1_kernel(
    const float* __restrict__ xw_f, const float* __restrict__ xw_b,
    const float* __restrict__ Whh_f, const float* __restrict__ bih_f, const float* __restrict__ bhh_f,
    const float* __restrict__ Whh_b, const float* __restrict__ bih_b, const float* __restrict__ bhh_b,
    unsigned short* __restrict__ h1b, float* __restrict__ state,
    int Tc, int t0f, int t0b, int first) {
  const int tid = threadIdx.x;
  const int j = tid & 127;
  const int p = tid >> 7;
  const int brow = blockIdx.x & 127;
  const int dir = blockIdx.x >> 7;
  const float* __restrict__ xw = dir ? xw_b : xw_f;
  const float* __restrict__ Whh = dir ? Whh_b : Whh_f;
  const float* __restrict__ bih = dir ? bih_b : bih_f;
  const float* __restrict__ bhh = dir ? bhh_b : bhh_f;
  const int t0 = dir ? t0b : t0f;

  float4 wh[4][8];
#pragma unroll
  for (int g = 0; g < 4; ++g) {
    const float4* wr = (const float4*)(Whh + (g * 128 + j) * 128 + p * 32);
#pragma unroll
    for (int f = 0; f < 8; ++f) wh[g][f] = wr[f];
  }
  const int myrow = p * 128 + j;
  const float bias = bih[myrow] + bhh[myrow];

  __shared__ float4 h4[32];
  __shared__ float4 part4[384];
  __shared__ float hring[8][128];
  float* sblk = state + (long)blockIdx.x * 256;
  float c = 0.0f;
  if (first) {
    if (tid < 32) h4[tid] = make_float4(0.f, 0.f, 0.f, 0.f);
  } else {
    if (tid < 128) ((float*)h4)[tid] = sblk[tid];
    if (!p) c = sblk[128 + j];
  }
  const long gbase = (long)brow * Tc;
  float xr[8];
#pragma unroll
  for (int v = 0; v < 8; ++v) {
    const int sn = v;
    xr[v] = 0.0f;
    if (sn < Tc) {
      const int tr = dir ? (Tc - 1 - sn) : sn;
      xr[v] = xw[(gbase + tr) * 512 + myrow];
    }
  }
  __syncthreads();

  const int nSB = (Tc + 7) / 8;
  for (int sb = 0; sb < nSB; ++sb) {
#pragma unroll
    for (int u = 0; u < 8; ++u) {
      const int s = sb * 8 + u;
      if (s >= Tc) break;
      float a0 = 0.f, a1 = 0.f, a2 = 0.f, a3 = 0.f;
#pragma unroll
      for (int f = 0; f < 8; ++f) {
        const float4 hv = h4[p * 8 + f];
        a0 += dot4(hv, wh[0][f]);
        a1 += dot4(hv, wh[1][f]);
        a2 += dot4(hv, wh[2][f]);
        a3 += dot4(hv, wh[3][f]);
      }
      const float xin = xr[u] + bias;
      if (p == 0) a0 += xin;
      else if (p == 1) a1 += xin;
      else if (p == 2) a2 += xin;
      else a3 += xin;
      if (p) part4[(p - 1) * 128 + j] = make_float4(a0, a1, a2, a3);
      __syncthreads();  // bar1
      if (!p) {
        const float4 q0 = part4[j], q1 = part4[128 + j], q2 = part4[256 + j];
        a0 += q0.x + q1.x + q2.x;
        a1 += q0.y + q1.y + q2.y;
        a2 += q0.z + q1.z + q2.z;
        a3 += q0.w + q1.w + q2.w;
        const float ig = sigf(a0);
        const float fg = sigf(a1);
        const float gg = tanh_fast(a2);
        const float og = sigf(a3);
        c = fg * c + ig * gg;
        const float hv = og * tanh_fast(c);
        ((float*)h4)[j] = hv;
        hring[u][j] = hv;
      }
      __syncthreads();  // bar2
      if (u == 7 || s + 1 == Tc) {
        if (p == 3) {  // bulk bf16 store of the group's h rows
#pragma unroll
          for (int v = 0; v < 8; ++v) {
            const int s2 = sb * 8 + v;
            if (s2 <= s) {
              const int tt = dir ? (Tc - 1 - s2) : s2;
              h1b[((long)brow * T_ + (t0 + tt)) * 256 + dir * 128 + j] = f2bf(hring[v][j]);
            }
          }
        }
        // refill xw group (all threads)
#pragma unroll
        for (int v = 0; v < 8; ++v) {
          const int sn = s + 1 + v;
          xr[v] = 0.0f;
          if (sn < Tc) {
            const int tr = dir ? (Tc - 1 - sn) : sn;
            xr[v] = xw[(gbase + tr) * 512 + myrow];
          }
        }
      }
    }
  }
  if (tid < 128) sblk[tid] = ((float*)h4)[tid];
  if (!p) sblk[128 + j] = c;
}

// ---------------- xw chunk = h0[slice] @ Wih1^T; M=128 x N=256 x K=256 per block ----------------
// grid (Tc, 4): dir = jt>>1, n-half = jt&1. A fetched once; B (512KB/dir) L2-resident.
// launch_bounds(256,1): acc[8][16]=128 VGPRs must live in registers (the (256,2)
// variant capped VGPR at 128 -> acc spilled to scratch -> 17.7 GB/dispatch of
// scratch traffic, round-4 regression).
__global__ __launch_bounds__(256, 1) void gemm_xw1(
    const float* __restrict__ h0,
    const float* __restrict__ Wf, const float* __restrict__ Wb,
    float* __restrict__ xwf, float* __restrict__ xwb,
    int Tc, int t0f, int t0b) {
  __shared__ float As[128][36];  // stride 36f: reads 2-way aliased (free)
  __shared__ float Bs[256][36];
  __shared__ int rowbase[128];
  const int tid = threadIdx.x;
  const int tx = tid & 15, ty = tid >> 4;
  const int r0 = blockIdx.x * 128;  // chunk-space row
  const int jt = blockIdx.y;
  const int dir = jt >> 1;
  const int nh = jt & 1;
  const float* __restrict__ W = dir ? Wb : Wf;
  float* __restrict__ out = dir ? xwb : xwf;
  const int jbase = nh * 256;
  const int t0 = dir ? t0b : t0f;

  if (tid < 128) {
    const int r = r0 + tid;
    const int br = r / Tc;
    rowbase[tid] = br * T_ + t0 + (r - br * Tc);
  }

  float acc[8][16] = {};
  float4* As4 = (float4*)As;  // row stride 9 float4
  float4* Bs4 = (float4*)Bs;
  for (int kk = 0; kk < 8; ++kk) {
    __syncthreads();
#pragma unroll
    for (int i = 0; i < 4; ++i) {
      const int q = tid + i * 256;
      const int row = q >> 3, k4 = q & 7;
      As4[row * 9 + k4] = *(const float4*)&h0[(long)rowbase[row] * 256 + kk * 32 + k4 * 4];
    }
#pragma unroll
    for (int i = 0; i < 8; ++i) {
      const int q = tid + i * 256;
      const int n = q >> 3, k4 = q & 7;
      Bs4[n * 9 + k4] = *(const float4*)&W[(long)(jbase + n) * 256 + kk * 32 + k4 * 4];
    }
    __syncthreads();
#pragma unroll
    for (int k4 = 0; k4 < 8; ++k4) {
      float4 av[8];
#pragma unroll
      for (int r = 0; r < 8; ++r) av[r] = As4[(ty + 16 * r) * 9 + k4];
#pragma unroll
      for (int c2 = 0; c2 < 16; ++c2) {
        const float4 bv = Bs4[(tx + 16 * c2) * 9 + k4];
#pragma unroll
        for (int r = 0; r < 8; ++r) acc[r][c2] += dot4(av[r], bv);
      }
    }
  }
#pragma unroll
  for (int r = 0; r < 8; ++r) {
    const long ob = (long)(r0 + ty + 16 * r) * 512 + jbase + tx;
#pragma unroll
    for (int c2 = 0; c2 < 16; ++c2) out[ob + c2 * 16] = acc[r][c2];
  }
}

// ---------------- attention scores: s = tanh(h1 @ W1^T + b1) @ w2 (h1 in bf16) ----------------
__global__ __launch_bounds__(256, 1) void score_kernel(
    const unsigned short* __restrict__ h1b, const float* __restrict__ W1,
    const float* __restrict__ b1, const float* __restrict__ w2,
    float* __restrict__ scores) {
  __shared__ float4 As[1152];
  __shared__ float4 Bs[1152];
  const int tid = threadIdx.x;
  const int tx = tid & 15, ty = tid >> 4;
  const long r0 = (long)blockIdx.x * 128;

  float acc[8][8] = {};
  for (int kk = 0; kk < 8; ++kk) {
    __syncthreads();
#pragma unroll
    for (int i = 0; i < 4; ++i) {
      const int q = tid + i * 256;
      const int row = q >> 3, kq = q & 7;
      const ushort4 uv = *(const ushort4*)&h1b[(r0 + row) * 256 + kk * 32 + kq * 4];
      As[row * 9 + kq] = bf4_to_f4(uv);
      Bs[row * 9 + kq] = *(const float4*)&W1[row * 256 + kk * 32 + kq * 4];
    }
    __syncthreads();
#pragma unroll
    for (int k4 = 0; k4 < 8; ++k4) {
      float4 bv[8];
#pragma unroll
      for (int jj = 0; jj < 8; ++jj) bv[jj] = Bs[(jj * 16 + tx) * 9 + k4];
#pragma unroll
      for (int rr = 0; rr < 8; ++rr) {
        const float4 av = As[(rr * 16 + ty) * 9 + k4];
#pragma unroll
        for (int jj = 0; jj < 8; ++jj) acc[rr][jj] += dot4(av, bv[jj]);
      }
    }
  }
  float pr[8];
#pragma unroll
  for (int rr = 0; rr < 8; ++rr) {
    float s = 0.0f;
#pragma unroll
    for (int jj = 0; jj < 8; ++jj) {
      const int col = jj * 16 + tx;
      s += tanh_fast(acc[rr][jj] + b1[col]) * w2[col];
    }
    pr[rr] = s;
  }
#pragma unroll
  for (int m = 1; m < 16; m <<= 1) {
#pragma unroll
    for (int rr = 0; rr < 8; ++rr) pr[rr] += __shfl_xor(pr[rr], m, 64);
  }
  if (tx == 0) {
#pragma unroll
    for (int rr = 0; rr < 8; ++rr) scores[r0 + rr * 16 + ty] = pr[rr];
  }
}

// ---------------- softmax over T + ctx + MLP head, one block per batch ----------------
__global__ __launch_bounds__(256, 2) void head_kernel(
    const float* __restrict__ scores, const unsigned short* __restrict__ h1b,
    const float* __restrict__ fW1, const float* __restrict__ fb1,
    const float* __restrict__ fW2, const float* __restrict__ fb2,
    float* __restrict__ outp) {
  const int b = blockIdx.x, tid = threadIdx.x;
  __shared__ float wls[1000];
  __shared__ float red[8];
  __shared__ __align__(16) float ctx[256];
  __shared__ __align__(16) float hid[128];

  float sv[4];
  float mx = -1e30f;
#pragma unroll
  for (int i = 0; i < 4; ++i) {
    const int t = tid + i * 256;
    sv[i] = (t < 1000) ? scores[b * 1000 + t] : -1e30f;
    mx = fmaxf(mx, sv[i]);
  }
  for (int m = 32; m; m >>= 1) mx = fmaxf(mx, __shfl_xor(mx, m, 64));
  if ((tid & 63) == 0) red[tid >> 6] = mx;
  __syncthreads();
  mx = fmaxf(fmaxf(red[0], red[1]), fmaxf(red[2], red[3]));
  float se = 0.0f;
#pragma unroll
  for (int i = 0; i < 4; ++i) {
    const int t = tid + i * 256;
    if (t < 1000) {
      const float e = __expf(sv[i] - mx);
      wls[t] = e;
      se += e;
    }
  }
  for (int m = 32; m; m >>= 1) se += __shfl_xor(se, m, 64);
  if ((tid & 63) == 0) red[4 + (tid >> 6)] = se;
  __syncthreads();
  const float rinv = 1.0f / (red[4] + red[5] + red[6] + red[7]);

  float a = 0.0f;
  const unsigned short* hb = h1b + (long)b * T_ * 256 + tid;
  for (int t = 0; t < T_; ++t) a = fmaf(wls[t], bf2f(hb[t * 256]), a);
  ctx[tid] = a * rinv;
  __syncthreads();
  if (tid < 128) {
    float s = fb1[tid];
    const float4* wr = (const float4*)&fW1[tid * 256];
    const float4* cc = (const float4*)ctx;
#pragma unroll
    for (int f = 0; f < 64; ++f) s += dot4(wr[f], cc[f]);
    hid[tid] = fmaxf(s, 0.0f);
  }
  __syncthreads();
  if (tid < 8) {
    float s = fb2[tid];
    const float4* wr = (const float4*)&fW2[tid * 128];
    const float4* hh = (const float4*)hid;
#pragma unroll
    for (int f = 0; f < 32; ++f) s += dot4(wr[f], hh[f]);
    outp[b * 8 + tid] = s;
  }
}

extern "C" void kernel_launch(void* const* d_in, const int* in_sizes, int n_in,
                              void* d_out, int out_size, void* d_ws, size_t ws_size,
                              hipStream_t stream) {
  (void)in_sizes; (void)n_in; (void)out_size;
  const float* x       = (const float*)d_in[0];
  const float* ln_g    = (const float*)d_in[1];
  const float* ln_b    = (const float*)d_in[2];
  const float* Wih_f0  = (const float*)d_in[3];
  const float* Whh_f0  = (const float*)d_in[4];
  const float* bih_f0  = (const float*)d_in[5];
  const float* bhh_f0  = (const float*)d_in[6];
  const float* Wih_b0  = (const float*)d_in[7];
  const float* Whh_b0  = (const float*)d_in[8];
  const float* bih_b0  = (const float*)d_in[9];
  const float* bhh_b0  = (const float*)d_in[10];
  const float* Wih_f1  = (const float*)d_in[11];
  const float* Whh_f1  = (const float*)d_in[12];
  const float* bih_f1  = (const float*)d_in[13];
  const float* bhh_f1  = (const float*)d_in[14];
  const float* Wih_b1  = (const float*)d_in[15];
  const float* Whh_b1  = (const float*)d_in[16];
  const float* bih_b1  = (const float*)d_in[17];
  const float* bhh_b1  = (const float*)d_in[18];
  const float* attn_W1 = (const float*)d_in[19];
  const float* attn_b1 = (const float*)d_in[20];
  const float* attn_w2 = (const float*)d_in[21];
  const float* fc_W1   = (const float*)d_in[22];
  const float* fc_b1   = (const float*)d_in[23];
  const float* fc_W2   = (const float*)d_in[24];
  const float* fc_b2   = (const float*)d_in[25];

  // ---- workspace layout (bytes), adapted to ws_size ----
  char* base = (char*)d_ws;
  size_t off = 0;
  auto alloc = [&](size_t bytes) {
    char* ptr = base + off;
    off += (bytes + 255) & ~(size_t)255;
    return ptr;
  };
  float*          h0    = (float*)alloc(32768000ull * 4);          // 131.1 MB
  unsigned short* h1b   = (unsigned short*)alloc(32768000ull * 2); //  65.5 MB
  float*          state = (float*)alloc(65536ull * 4);             //   0.26 MB
  float*          scor  = (float*)alloc(128000ull * 4);            //   0.51 MB

  const size_t rem = (ws_size > off) ? (ws_size - off) : 0;
  static const int cands[16] = {1000, 500, 250, 200, 125, 100, 50, 40, 25, 20, 10, 8, 5, 4, 2, 1};
  int Tc = 0;
  for (int ci = 0; ci < 16; ++ci) {
    if (524288ull * (size_t)cands[ci] <= rem) { Tc = cands[ci]; break; }
  }
  if (Tc == 0) {  // workspace too small for any plan: clean numeric fail (diagnostic)
    bail_kernel<<<dim3(1), dim3(256), 0, stream>>>((float*)d_out, 1024);
    return;
  }
  float* xwf = (float*)(base + off);
  float* xwb = xwf + 65536L * Tc;

  rec0_kernel<<<dim3(256), dim3(512), 0, stream>>>(x, ln_g, ln_b,
                                                   Wih_f0, Whh_f0, bih_f0, bhh_f0,
                                                   Wih_b0, Whh_b0, bih_b0, bhh_b0, h0);
  const int nch = T_ / Tc;
  for (int ch = 0; ch < nch; ++ch) {
    const int t0f = ch * Tc;
    const int t0b = T_ - (ch + 1) * Tc;
    gemm_xw1<<<dim3(Tc, 4), dim3(256), 0, stream>>>(h0, Wih_f1, Wih_b1, xwf, xwb, Tc, t0f, t0b);
    rec1_kernel<<<dim3(256), dim3(512), 0, stream>>>(xwf, xwb, Whh_f1, bih_f1, bhh_f1,
                                                     Whh_b1, bih_b1, bhh_b1, h1b, state,
                                                     Tc, t0f, t0b, (ch == 0) ? 1 : 0);
  }
  score_kernel<<<dim3(1000), dim3(256), 0, stream>>>(h1b, attn_W1, attn_b1, attn_w2, scor);
  head_kernel<<<dim3(128), dim3(256), 0, stream>>>(scor, h1b, fc_W1, fc_b1, fc_W2, fc_b2,
                                                   (float*)d_out);
}

// Round 6
// 3588.687 us; speedup vs baseline: 16.2290x; 16.2290x over previous
//
#include <hip/hip_runtime.h>

#define T_ 1000

__device__ __forceinline__ float sigf(float x) { return 1.0f / (1.0f + __expf(-x)); }
__device__ __forceinline__ float tanh_fast(float x) { return 1.0f - 2.0f / (1.0f + __expf(2.0f * x)); }
__device__ __forceinline__ float dot4(float4 a, float4 b) {
  return a.x * b.x + a.y * b.y + a.z * b.z + a.w * b.w;
}
__device__ __forceinline__ unsigned short f2bf(float f) {
  unsigned u = __float_as_uint(f);
  u = (u + 0x7fffu + ((u >> 16) & 1u)) >> 16;  // RNE
  return (unsigned short)u;
}
__device__ __forceinline__ float bf2f(unsigned short h) {
  return __uint_as_float(((unsigned)h) << 16);
}
__device__ __forceinline__ float4 bf4_to_f4(ushort4 u) {
  float4 r;
  r.x = bf2f(u.x); r.y = bf2f(u.y); r.z = bf2f(u.z); r.w = bf2f(u.w);
  return r;
}

__global__ void bail_kernel(float* out, int n) {
  for (int i = threadIdx.x; i < n; i += 256) out[i] = 0.0f;
}

// ---------------- Layer-0 recurrence with fused LayerNorm, 1 block per (row,dir) ----------------
__global__ __launch_bounds__(512, 2) void rec0_kernel(
    const float* __restrict__ x,
    const float* __restrict__ ln_g, const float* __restrict__ ln_b,
    const float* __restrict__ Wih_f, const float* __restrict__ Whh_f,
    const float* __restrict__ bih_f, const float* __restrict__ bhh_f,
    const float* __restrict__ Wih_b, const float* __restrict__ Whh_b,
    const float* __restrict__ bih_b, const float* __restrict__ bhh_b,
    float* __restrict__ h0) {
  const int tid = threadIdx.x;
  const int j = tid & 127;
  const int p = tid >> 7;
  const int brow = blockIdx.x & 127;
  const int dir = blockIdx.x >> 7;
  const float* __restrict__ Wih = dir ? Wih_b : Wih_f;
  const float* __restrict__ Whh = dir ? Whh_b : Whh_f;
  const float* __restrict__ bih = dir ? bih_b : bih_f;
  const float* __restrict__ bhh = dir ? bhh_b : bhh_f;

  float4 wh[4][8];
  float4 wi[4][3];
#pragma unroll
  for (int g = 0; g < 4; ++g) {
    const int row = g * 128 + j;
    const float4* wr = (const float4*)(Whh + row * 128 + p * 32);
#pragma unroll
    for (int f = 0; f < 8; ++f) wh[g][f] = wr[f];
    const float* xr_ = Wih + row * 40;
#pragma unroll
    for (int f = 0; f < 3; ++f) {
      const int k0 = p * 12 + f * 4;
      float4 tv;
      tv.x = (k0 + 0 < 40) ? xr_[k0 + 0] : 0.0f;
      tv.y = (k0 + 1 < 40) ? xr_[k0 + 1] : 0.0f;
      tv.z = (k0 + 2 < 40) ? xr_[k0 + 2] : 0.0f;
      tv.w = (k0 + 3 < 40) ? xr_[k0 + 3] : 0.0f;
      wi[g][f] = tv;
    }
  }
  const float bias = bih[p * 128 + j] + bhh[p * 128 + j];
  const float b0 = (p == 0) ? bias : 0.0f;
  const float b1 = (p == 1) ? bias : 0.0f;
  const float b2 = (p == 2) ? bias : 0.0f;
  const float b3 = (p == 3) ? bias : 0.0f;

  __shared__ float4 h4[32];
  __shared__ float4 x4[12];
  __shared__ float4 part4[384];
  __shared__ float hring[8][128];

  float gj = 0.0f, bj = 0.0f;
  if (p == 1 && j < 40) { gj = ln_g[j]; bj = ln_b[j]; }

  if (tid < 32) h4[tid] = make_float4(0.f, 0.f, 0.f, 0.f);
  if (tid >= 40 && tid < 48) ((float*)x4)[tid] = 0.0f;
  __syncthreads();

  const long xbase = (long)brow * T_ * 40;
  float xr[8];
  if (p == 1 && j < 64) {
    const long tA = dir ? (T_ - 1) : 0;
    float v = (j < 40) ? x[xbase + tA * 40 + j] : 0.0f;
    float s1 = v, s2 = v * v;
#pragma unroll
    for (int m = 32; m; m >>= 1) {
      s1 += __shfl_xor(s1, m, 64);
      s2 += __shfl_xor(s2, m, 64);
    }
    const float mu = s1 * (1.0f / 40.0f);
    const float var = s2 * (1.0f / 40.0f) - mu * mu;
    const float rs = rsqrtf(var + 1e-5f);
    if (j < 40) ((float*)x4)[j] = (v - mu) * rs * gj + bj;
#pragma unroll
    for (int v8 = 0; v8 < 8; ++v8) {
      const int tr = 1 + v8;
      xr[v8] = 0.0f;
      if (j < 40 && tr < T_) {
        const long tt = dir ? (T_ - 1 - tr) : tr;
        xr[v8] = x[xbase + tt * 40 + j];
      }
    }
  }
  float c = 0.0f;
  __syncthreads();

  const long hbase = (long)brow * T_ * 256;
  for (int sb = 0; sb < 125; ++sb) {
#pragma unroll
    for (int u = 0; u < 8; ++u) {
      const int t = sb * 8 + u;
      float a0 = b0, a1 = b1, a2 = b2, a3 = b3;
#pragma unroll
      for (int f = 0; f < 3; ++f) {
        const float4 xv = x4[p * 3 + f];
        a0 += dot4(xv, wi[0][f]);
        a1 += dot4(xv, wi[1][f]);
        a2 += dot4(xv, wi[2][f]);
        a3 += dot4(xv, wi[3][f]);
      }
#pragma unroll
      for (int f = 0; f < 8; ++f) {
        const float4 hv = h4[p * 8 + f];
        a0 += dot4(hv, wh[0][f]);
        a1 += dot4(hv, wh[1][f]);
        a2 += dot4(hv, wh[2][f]);
        a3 += dot4(hv, wh[3][f]);
      }
      if (p) part4[(p - 1) * 128 + j] = make_float4(a0, a1, a2, a3);
      __syncthreads();  // bar1
      if (!p) {
        const float4 q0 = part4[j], q1 = part4[128 + j], q2 = part4[256 + j];
        a0 += q0.x + q1.x + q2.x;
        a1 += q0.y + q1.y + q2.y;
        a2 += q0.z + q1.z + q2.z;
        a3 += q0.w + q1.w + q2.w;
        const float ig = sigf(a0);
        const float fg = sigf(a1);
        const float gg = tanh_fast(a2);
        const float og = sigf(a3);
        c = fg * c + ig * gg;
        const float hv = og * tanh_fast(c);
        ((float*)h4)[j] = hv;
        hring[u][j] = hv;
      } else if (p == 1 && j < 64) {
        if (t + 1 < T_) {
          float v = xr[u];
          float s1 = v, s2 = v * v;
#pragma unroll
          for (int m = 32; m; m >>= 1) {
            s1 += __shfl_xor(s1, m, 64);
            s2 += __shfl_xor(s2, m, 64);
          }
          const float mu = s1 * (1.0f / 40.0f);
          const float var = s2 * (1.0f / 40.0f) - mu * mu;
          const float rs = rsqrtf(var + 1e-5f);
          if (j < 40) ((float*)x4)[j] = (v - mu) * rs * gj + bj;
        }
      }
      __syncthreads();  // bar2
      if (u == 7) {
        if (p == 3) {
#pragma unroll
          for (int v = 0; v < 8; ++v) {
            const int ts = sb * 8 + v;
            const int te = dir ? (T_ - 1 - ts) : ts;
            h0[hbase + (long)te * 256 + dir * 128 + j] = hring[v][j];
          }
        } else if (p == 1 && j < 64) {
#pragma unroll
          for (int v = 0; v < 8; ++v) {
            const int tr = sb * 8 + 9 + v;
            xr[v] = 0.0f;
            if (j < 40 && tr < T_) {
              const long tt = dir ? (T_ - 1 - tr) : tr;
              xr[v] = x[xbase + tt * 40 + j];
            }
          }
        }
      }
    }
  }
}

// ---------------- Layer-1 recurrence, time-chunked ----------------
__global__ __launch_bounds__(512, 2) void rec1_kernel(
    const float* __restrict__ xw_f, const float* __restrict__ xw_b,
    const float* __restrict__ Whh_f, const float* __restrict__ bih_f, const float* __restrict__ bhh_f,
    const float* __restrict__ Whh_b, const float* __restrict__ bih_b, const float* __restrict__ bhh_b,
    unsigned short* __restrict__ h1b, float* __restrict__ state,
    int Tc, int t0f, int t0b, int first) {
  const int tid = threadIdx.x;
  const int j = tid & 127;
  const int p = tid >> 7;
  const int brow = blockIdx.x & 127;
  const int dir = blockIdx.x >> 7;
  const float* __restrict__ xw = dir ? xw_b : xw_f;
  const float* __restrict__ Whh = dir ? Whh_b : Whh_f;
  const float* __restrict__ bih = dir ? bih_b : bih_f;
  const float* __restrict__ bhh = dir ? bhh_b : bhh_f;
  const int t0 = dir ? t0b : t0f;

  float4 wh[4][8];
#pragma unroll
  for (int g = 0; g < 4; ++g) {
    const float4* wr = (const float4*)(Whh + (g * 128 + j) * 128 + p * 32);
#pragma unroll
    for (int f = 0; f < 8; ++f) wh[g][f] = wr[f];
  }
  const int myrow = p * 128 + j;
  const float bias = bih[myrow] + bhh[myrow];

  __shared__ float4 h4[32];
  __shared__ float4 part4[384];
  __shared__ float hring[8][128];
  float* sblk = state + (long)blockIdx.x * 256;
  float c = 0.0f;
  if (first) {
    if (tid < 32) h4[tid] = make_float4(0.f, 0.f, 0.f, 0.f);
  } else {
    if (tid < 128) ((float*)h4)[tid] = sblk[tid];
    if (!p) c = sblk[128 + j];
  }
  const long gbase = (long)brow * Tc;
  float xr[8];
#pragma unroll
  for (int v = 0; v < 8; ++v) {
    const int sn = v;
    xr[v] = 0.0f;
    if (sn < Tc) {
      const int tr = dir ? (Tc - 1 - sn) : sn;
      xr[v] = xw[(gbase + tr) * 512 + myrow];
    }
  }
  __syncthreads();

  const int nSB = (Tc + 7) / 8;
  for (int sb = 0; sb < nSB; ++sb) {
#pragma unroll
    for (int u = 0; u < 8; ++u) {
      const int s = sb * 8 + u;
      if (s >= Tc) break;
      float a0 = 0.f, a1 = 0.f, a2 = 0.f, a3 = 0.f;
#pragma unroll
      for (int f = 0; f < 8; ++f) {
        const float4 hv = h4[p * 8 + f];
        a0 += dot4(hv, wh[0][f]);
        a1 += dot4(hv, wh[1][f]);
        a2 += dot4(hv, wh[2][f]);
        a3 += dot4(hv, wh[3][f]);
      }
      const float xin = xr[u] + bias;
      if (p == 0) a0 += xin;
      else if (p == 1) a1 += xin;
      else if (p == 2) a2 += xin;
      else a3 += xin;
      if (p) part4[(p - 1) * 128 + j] = make_float4(a0, a1, a2, a3);
      __syncthreads();  // bar1
      if (!p) {
        const float4 q0 = part4[j], q1 = part4[128 + j], q2 = part4[256 + j];
        a0 += q0.x + q1.x + q2.x;
        a1 += q0.y + q1.y + q2.y;
        a2 += q0.z + q1.z + q2.z;
        a3 += q0.w + q1.w + q2.w;
        const float ig = sigf(a0);
        const float fg = sigf(a1);
        const float gg = tanh_fast(a2);
        const float og = sigf(a3);
        c = fg * c + ig * gg;
        const float hv = og * tanh_fast(c);
        ((float*)h4)[j] = hv;
        hring[u][j] = hv;
      }
      __syncthreads();  // bar2
      if (u == 7 || s + 1 == Tc) {
        if (p == 3) {
#pragma unroll
          for (int v = 0; v < 8; ++v) {
            const int s2 = sb * 8 + v;
            if (s2 <= s) {
              const int tt = dir ? (Tc - 1 - s2) : s2;
              h1b[((long)brow * T_ + (t0 + tt)) * 256 + dir * 128 + j] = f2bf(hring[v][j]);
            }
          }
        }
#pragma unroll
        for (int v = 0; v < 8; ++v) {
          const int sn = s + 1 + v;
          xr[v] = 0.0f;
          if (sn < Tc) {
            const int tr = dir ? (Tc - 1 - sn) : sn;
            xr[v] = xw[(gbase + tr) * 512 + myrow];
          }
        }
      }
    }
  }
  if (tid < 128) sblk[tid] = ((float*)h4)[tid];
  if (!p) sblk[128 + j] = c;
}

// ---------------- xw chunk GEMM: tile M=64 x N=128, K-step 32, micro 4x8 ----------------
// Liveness bounded by DESIGN: acc[4][8]=32 regs; kk and k4 loops forced rolled
// (#pragma unroll 1) so the compiler cannot pipeline 8 k-slices of LDS reads into
// registers (that pipelining is what pushed rounds 3-5 past the 256-VGPR ISA cap
// and spilled acc to scratch: 15 GB/dispatch of scratch traffic at 3% VALUBusy).
__global__ __launch_bounds__(256, 2) void gemm_xw1(
    const float* __restrict__ h0,
    const float* __restrict__ Wf, const float* __restrict__ Wb,
    float* __restrict__ xwf, float* __restrict__ xwb,
    int Tc, int t0f, int t0b) {
  __shared__ float As[64 * 36];   // 64 rows x 9 float4 (pad: +1 f4 per row)
  __shared__ float Bs[128 * 36];
  __shared__ int rowbase[64];
  const int tid = threadIdx.x;
  const int tx = tid & 15, ty = tid >> 4;
  const int r0 = blockIdx.x * 64;   // chunk-space row
  const int jt = blockIdx.y;        // 0..7
  const int dir = jt >> 2;
  const int nh = jt & 3;
  const float* __restrict__ W = dir ? Wb : Wf;
  float* __restrict__ out = dir ? xwb : xwf;
  const int jbase = nh * 128;
  const int t0 = dir ? t0b : t0f;

  if (tid < 64) {
    const int r = r0 + tid;
    const int br = r / Tc;
    rowbase[tid] = br * T_ + t0 + (r - br * Tc);
  }

  float4* As4 = (float4*)As;
  float4* Bs4 = (float4*)Bs;
  float acc[4][8] = {};
#pragma unroll 1
  for (int kk = 0; kk < 8; ++kk) {
    __syncthreads();  // also covers rowbase on kk==0
#pragma unroll
    for (int i = 0; i < 2; ++i) {  // A: 512 f4, 2/thread
      const int q = tid + i * 256;
      const int row = q >> 3, k4 = q & 7;
      As4[row * 9 + k4] = *(const float4*)&h0[(long)rowbase[row] * 256 + kk * 32 + k4 * 4];
    }
#pragma unroll
    for (int i = 0; i < 4; ++i) {  // B: 1024 f4, 4/thread
      const int q = tid + i * 256;
      const int row = q >> 3, k4 = q & 7;
      Bs4[row * 9 + k4] = *(const float4*)&W[(long)(jbase + row) * 256 + kk * 32 + k4 * 4];
    }
    __syncthreads();
#pragma unroll 1
    for (int k4 = 0; k4 < 8; ++k4) {
      float4 av[4];
#pragma unroll
      for (int r = 0; r < 4; ++r) av[r] = As4[(ty * 4 + r) * 9 + k4];
#pragma unroll
      for (int c2 = 0; c2 < 8; ++c2) {
        const float4 bv = Bs4[(tx + 16 * c2) * 9 + k4];
#pragma unroll
        for (int r = 0; r < 4; ++r) acc[r][c2] += dot4(av[r], bv);
      }
    }
  }
#pragma unroll
  for (int r = 0; r < 4; ++r) {
    const long ob = (long)(r0 + ty * 4 + r) * 512 + jbase + tx;
#pragma unroll
    for (int c2 = 0; c2 < 8; ++c2) out[ob + c2 * 16] = acc[r][c2];
  }
}

// ---------------- attention scores: tile 64 rows x 128 cols, same bounded pattern ----------------
__global__ __launch_bounds__(256, 2) void score_kernel(
    const unsigned short* __restrict__ h1b, const float* __restrict__ W1,
    const float* __restrict__ b1, const float* __restrict__ w2,
    float* __restrict__ scores) {
  __shared__ float As[64 * 36];
  __shared__ float Bs[128 * 36];
  const int tid = threadIdx.x;
  const int tx = tid & 15, ty = tid >> 4;
  const long r0 = (long)blockIdx.x * 64;

  float4* As4 = (float4*)As;
  float4* Bs4 = (float4*)Bs;
  float acc[4][8] = {};
#pragma unroll 1
  for (int kk = 0; kk < 8; ++kk) {
    __syncthreads();
#pragma unroll
    for (int i = 0; i < 2; ++i) {
      const int q = tid + i * 256;
      const int row = q >> 3, k4 = q & 7;
      const ushort4 uv = *(const ushort4*)&h1b[(r0 + row) * 256 + kk * 32 + k4 * 4];
      As4[row * 9 + k4] = bf4_to_f4(uv);
    }
#pragma unroll
    for (int i = 0; i < 4; ++i) {
      const int q = tid + i * 256;
      const int row = q >> 3, k4 = q & 7;
      Bs4[row * 9 + k4] = *(const float4*)&W1[(long)row * 256 + kk * 32 + k4 * 4];
    }
    __syncthreads();
#pragma unroll 1
    for (int k4 = 0; k4 < 8; ++k4) {
      float4 av[4];
#pragma unroll
      for (int r = 0; r < 4; ++r) av[r] = As4[(ty * 4 + r) * 9 + k4];
#pragma unroll
      for (int c2 = 0; c2 < 8; ++c2) {
        const float4 bv = Bs4[(tx + 16 * c2) * 9 + k4];
#pragma unroll
        for (int r = 0; r < 4; ++r) acc[r][c2] += dot4(av[r], bv);
      }
    }
  }
#pragma unroll
  for (int r = 0; r < 4; ++r) {
    float s = 0.0f;
#pragma unroll
    for (int c2 = 0; c2 < 8; ++c2) {
      const int col = tx + 16 * c2;
      s += tanh_fast(acc[r][c2] + b1[col]) * w2[col];
    }
#pragma unroll
    for (int m = 1; m < 16; m <<= 1) s += __shfl_xor(s, m, 16);
    if (tx == 0) scores[r0 + ty * 4 + r] = s;
  }
}

// ---------------- softmax over T + ctx + MLP head, one block per batch ----------------
__global__ __launch_bounds__(256, 2) void head_kernel(
    const float* __restrict__ scores, const unsigned short* __restrict__ h1b,
    const float* __restrict__ fW1, const float* __restrict__ fb1,
    const float* __restrict__ fW2, const float* __restrict__ fb2,
    float* __restrict__ outp) {
  const int b = blockIdx.x, tid = threadIdx.x;
  __shared__ float wls[1000];
  __shared__ float red[8];
  __shared__ __align__(16) float ctx[256];
  __shared__ __align__(16) float hid[128];

  float sv[4];
  float mx = -1e30f;
#pragma unroll
  for (int i = 0; i < 4; ++i) {
    const int t = tid + i * 256;
    sv[i] = (t < 1000) ? scores[b * 1000 + t] : -1e30f;
    mx = fmaxf(mx, sv[i]);
  }
  for (int m = 32; m; m >>= 1) mx = fmaxf(mx, __shfl_xor(mx, m, 64));
  if ((tid & 63) == 0) red[tid >> 6] = mx;
  __syncthreads();
  mx = fmaxf(fmaxf(red[0], red[1]), fmaxf(red[2], red[3]));
  float se = 0.0f;
#pragma unroll
  for (int i = 0; i < 4; ++i) {
    const int t = tid + i * 256;
    if (t < 1000) {
      const float e = __expf(sv[i] - mx);
      wls[t] = e;
      se += e;
    }
  }
  for (int m = 32; m; m >>= 1) se += __shfl_xor(se, m, 64);
  if ((tid & 63) == 0) red[4 + (tid >> 6)] = se;
  __syncthreads();
  const float rinv = 1.0f / (red[4] + red[5] + red[6] + red[7]);

  float a = 0.0f;
  const unsigned short* hb = h1b + (long)b * T_ * 256 + tid;
  for (int t = 0; t < T_; ++t) a = fmaf(wls[t], bf2f(hb[t * 256]), a);
  ctx[tid] = a * rinv;
  __syncthreads();
  if (tid < 128) {
    float s = fb1[tid];
    const float4* wr = (const float4*)&fW1[tid * 256];
    const float4* cc = (const float4*)ctx;
#pragma unroll
    for (int f = 0; f < 64; ++f) s += dot4(wr[f], cc[f]);
    hid[tid] = fmaxf(s, 0.0f);
  }
  __syncthreads();
  if (tid < 8) {
    float s = fb2[tid];
    const float4* wr = (const float4*)&fW2[tid * 128];
    const float4* hh = (const float4*)hid;
#pragma unroll
    for (int f = 0; f < 32; ++f) s += dot4(wr[f], hh[f]);
    outp[b * 8 + tid] = s;
  }
}

extern "C" void kernel_launch(void* const* d_in, const int* in_sizes, int n_in,
                              void* d_out, int out_size, void* d_ws, size_t ws_size,
                              hipStream_t stream) {
  (void)in_sizes; (void)n_in; (void)out_size;
  const float* x       = (const float*)d_in[0];
  const float* ln_g    = (const float*)d_in[1];
  const float* ln_b    = (const float*)d_in[2];
  const float* Wih_f0  = (const float*)d_in[3];
  const float* Whh_f0  = (const float*)d_in[4];
  const float* bih_f0  = (const float*)d_in[5];
  const float* bhh_f0  = (const float*)d_in[6];
  const float* Wih_b0  = (const float*)d_in[7];
  const float* Whh_b0  = (const float*)d_in[8];
  const float* bih_b0  = (const float*)d_in[9];
  const float* bhh_b0  = (const float*)d_in[10];
  const float* Wih_f1  = (const float*)d_in[11];
  const float* Whh_f1  = (const float*)d_in[12];
  const float* bih_f1  = (const float*)d_in[13];
  const float* bhh_f1  = (const float*)d_in[14];
  const float* Wih_b1  = (const float*)d_in[15];
  const float* Whh_b1  = (const float*)d_in[16];
  const float* bih_b1  = (const float*)d_in[17];
  const float* bhh_b1  = (const float*)d_in[18];
  const float* attn_W1 = (const float*)d_in[19];
  const float* attn_b1 = (const float*)d_in[20];
  const float* attn_w2 = (const float*)d_in[21];
  const float* fc_W1   = (const float*)d_in[22];
  const float* fc_b1   = (const float*)d_in[23];
  const float* fc_W2   = (const float*)d_in[24];
  const float* fc_b2   = (const float*)d_in[25];

  // ---- workspace layout (bytes), adapted to ws_size ----
  char* base = (char*)d_ws;
  size_t off = 0;
  auto alloc = [&](size_t bytes) {
    char* ptr = base + off;
    off += (bytes + 255) & ~(size_t)255;
    return ptr;
  };
  float*          h0    = (float*)alloc(32768000ull * 4);          // 131.1 MB
  unsigned short* h1b   = (unsigned short*)alloc(32768000ull * 2); //  65.5 MB
  float*          state = (float*)alloc(65536ull * 4);             //   0.26 MB
  float*          scor  = (float*)alloc(128000ull * 4);            //   0.51 MB

  const size_t rem = (ws_size > off) ? (ws_size - off) : 0;
  static const int cands[16] = {1000, 500, 250, 200, 125, 100, 50, 40, 25, 20, 10, 8, 5, 4, 2, 1};
  int Tc = 0;
  for (int ci = 0; ci < 16; ++ci) {
    if (524288ull * (size_t)cands[ci] <= rem) { Tc = cands[ci]; break; }
  }
  if (Tc == 0) {
    bail_kernel<<<dim3(1), dim3(256), 0, stream>>>((float*)d_out, 1024);
    return;
  }
  float* xwf = (float*)(base + off);
  float* xwb = xwf + 65536L * Tc;

  rec0_kernel<<<dim3(256), dim3(512), 0, stream>>>(x, ln_g, ln_b,
                                                   Wih_f0, Whh_f0, bih_f0, bhh_f0,
                                                   Wih_b0, Whh_b0, bih_b0, bhh_b0, h0);
  const int nch = T_ / Tc;
  for (int ch = 0; ch < nch; ++ch) {
    const int t0f = ch * Tc;
    const int t0b = T_ - (ch + 1) * Tc;
    gemm_xw1<<<dim3(2 * Tc, 8), dim3(256), 0, stream>>>(h0, Wih_f1, Wih_b1, xwf, xwb, Tc, t0f, t0b);
    rec1_kernel<<<dim3(256), dim3(512), 0, stream>>>(xwf, xwb, Whh_f1, bih_f1, bhh_f1,
                                                     Whh_b1, bih_b1, bhh_b1, h1b, state,
                                                     Tc, t0f, t0b, (ch == 0) ? 1 : 0);
  }
  score_kernel<<<dim3(2000), dim3(256), 0, stream>>>(h1b, attn_W1, attn_b1, attn_w2, scor);
  head_kernel<<<dim3(128), dim3(256), 0, stream>>>(scor, h1b, fc_W1, fc_b1, fc_W2, fc_b2,
                                                   (float*)d_out);
}

// Round 7
// 2887.410 us; speedup vs baseline: 20.1706x; 1.2429x over previous
//
#include <hip/hip_runtime.h>

#define T_ 1000

typedef float v2f __attribute__((ext_vector_type(2)));

__device__ __forceinline__ float sigf(float x) { return 1.0f / (1.0f + __expf(-x)); }
__device__ __forceinline__ float tanh_fast(float x) { return 1.0f - 2.0f / (1.0f + __expf(2.0f * x)); }
__device__ __forceinline__ float dot4(float4 a, float4 b) {
  return a.x * b.x + a.y * b.y + a.z * b.z + a.w * b.w;
}
__device__ __forceinline__ void pkfma(v2f& acc, float4 w, float4 v) {
  v2f wl; wl[0] = w.x; wl[1] = w.y;
  v2f wh; wh[0] = w.z; wh[1] = w.w;
  v2f vl; vl[0] = v.x; vl[1] = v.y;
  v2f vh; vh[0] = v.z; vh[1] = v.w;
  acc += wl * vl;
  acc += wh * vh;
}
__device__ __forceinline__ unsigned short f2bf(float f) {
  unsigned u = __float_as_uint(f);
  u = (u + 0x7fffu + ((u >> 16) & 1u)) >> 16;  // RNE
  return (unsigned short)u;
}
__device__ __forceinline__ float bf2f(unsigned short h) {
  return __uint_as_float(((unsigned)h) << 16);
}
__device__ __forceinline__ float4 bf4_to_f4(ushort4 u) {
  float4 r;
  r.x = bf2f(u.x); r.y = bf2f(u.y); r.z = bf2f(u.z); r.w = bf2f(u.w);
  return r;
}

__global__ void bail_kernel(float* out, int n) {
  for (int i = threadIdx.x; i < n; i += 256) out[i] = 0.0f;
}

// ---------------- LN stats: per row (mu, rs) ----------------
__global__ __launch_bounds__(256) void ln_stats_kernel(const float* __restrict__ x,
                                                       float* __restrict__ mu_arr,
                                                       float* __restrict__ rs_arr) {
  const int lane = threadIdx.x & 63;
  const int w = threadIdx.x >> 6;
  const long row = (long)blockIdx.x * 4 + w;
  float v = (lane < 40) ? x[row * 40 + lane] : 0.0f;
  float s1 = v, s2 = v * v;
  for (int m = 32; m; m >>= 1) {
    s1 += __shfl_xor(s1, m, 64);
    s2 += __shfl_xor(s2, m, 64);
  }
  if (lane == 0) {
    const float mu = s1 * (1.0f / 40.0f);
    const float var = s2 * (1.0f / 40.0f) - mu * mu;
    mu_arr[row] = mu;
    rs_arr[row] = rsqrtf(var + 1e-5f);
  }
}

// ---------------- Layer-0 recurrence: quad-mapped k-split, 1 barrier/step ----------------
// lane: unit u = (wave)*16 + (lane_in_wave>>2), k-quarter p = lane&3.
// Gate partials reduced across the quad via 2 shfl_xor; combine replicated in all lanes
// (c replicated per quad). LN folded into Wih via precomputed (mu,rs) + S1/S2 constants.
__global__ __launch_bounds__(512, 1) void rec0_kernel(
    const float* __restrict__ x,
    const float* __restrict__ mu_arr, const float* __restrict__ rs_arr,
    const float* __restrict__ ln_g, const float* __restrict__ ln_b,
    const float* __restrict__ Wih_f, const float* __restrict__ Whh_f,
    const float* __restrict__ bih_f, const float* __restrict__ bhh_f,
    const float* __restrict__ Wih_b, const float* __restrict__ Whh_b,
    const float* __restrict__ bih_b, const float* __restrict__ bhh_b,
    float* __restrict__ h0) {
  const int tid = threadIdx.x;
  const int u = (tid >> 6) * 16 + ((tid & 63) >> 2);
  const int p = tid & 3;
  const int brow = blockIdx.x & 127;
  const int dir = blockIdx.x >> 7;
  const float* __restrict__ Wih = dir ? Wih_b : Wih_f;
  const float* __restrict__ Whh = dir ? Whh_b : Whh_f;
  const float* __restrict__ bih = dir ? bih_b : bih_f;
  const float* __restrict__ bhh = dir ? bhh_b : bhh_f;

  // Whh fragments, pre-rotated so step-loop reads h4 at bank-disjoint quads:
  // wh[g][ff] pairs with h-quad ((ff+2p)&7).
  float4 wh[4][8];
  float4 wi[4][3];
  float S1[4], bias[4];
#pragma unroll
  for (int g = 0; g < 4; ++g) {
    const int row = g * 128 + u;
    const float4* wr = (const float4*)(Whh + row * 128 + p * 32);
#pragma unroll
    for (int ff = 0; ff < 8; ++ff) wh[g][ff] = wr[(ff + 2 * p) & 7];
    float s1p = 0.0f, s2p = 0.0f;
#pragma unroll
    for (int f = 0; f < 3; ++f) {
      float tmp[4];
#pragma unroll
      for (int e = 0; e < 4; ++e) {
        const int k = p * 12 + f * 4 + e;
        const float wv = (k < 40) ? Wih[row * 40 + k] : 0.0f;
        const float gk = (k < 40) ? ln_g[k] : 0.0f;
        const float bk = (k < 40) ? ln_b[k] : 0.0f;
        const float wf = wv * gk;
        tmp[e] = wf;
        s1p += wf;
        s2p += wv * bk;
      }
      wi[g][f] = make_float4(tmp[0], tmp[1], tmp[2], tmp[3]);
    }
    s1p += __shfl_xor(s1p, 1, 64); s1p += __shfl_xor(s1p, 2, 64);
    s2p += __shfl_xor(s2p, 1, 64); s2p += __shfl_xor(s2p, 2, 64);
    S1[g] = s1p;
    bias[g] = bih[g * 128 + u] + bhh[g * 128 + u] + s2p;
  }

  __shared__ float h4f[128];
  __shared__ __align__(16) float x_ring[2][8][48];
  __shared__ float mu_ring[2][8], rs_ring[2][8];
  __shared__ float hring[2][8][128];

  const int lr8 = tid / 40;          // x-prefetch row (tid<320)
  const int lcol = tid - lr8 * 40;   // x-prefetch col
  const long xbase = (long)brow * T_ * 40;
  const long mbase = (long)brow * T_;
  const long hbase = (long)brow * T_ * 256;

  // init: zero h, zero x-ring pad, stage group 0
  if (tid < 128) h4f[tid] = 0.0f;
  if (tid < 128) {  // pad cols 40..47, both buffers
    const int b = tid >> 6, r = (tid >> 3) & 7, cc = 40 + (tid & 7);
    x_ring[b][r][cc] = 0.0f;
  }
  if (tid < 320) {
    const int t = lr8;
    const int tt = dir ? (T_ - 1 - t) : t;
    x_ring[0][lr8][lcol] = x[xbase + (long)tt * 40 + lcol];
  } else if (tid < 328) {
    const int t = tid - 320;
    const int tt = dir ? (T_ - 1 - t) : t;
    mu_ring[0][t] = mu_arr[mbase + tt];
  } else if (tid < 336) {
    const int t = tid - 328;
    const int tt = dir ? (T_ - 1 - t) : t;
    rs_ring[0][t] = rs_arr[mbase + tt];
  }
  float c = 0.0f;
  float xpf = 0.0f, mupf = 0.0f, rspf = 0.0f;
  __syncthreads();

  for (int sb = 0; sb < 125; ++sb) {
    const int rb = sb & 1;
#pragma unroll
    for (int su = 0; su < 8; ++su) {
      if (su == 0) {
        if (sb + 1 < 125) {  // issue next-group prefetch (regs)
          if (tid < 320) {
            const int t = (sb + 1) * 8 + lr8;
            const int tt = dir ? (T_ - 1 - t) : t;
            xpf = x[xbase + (long)tt * 40 + lcol];
          } else if (tid < 328) {
            const int t = (sb + 1) * 8 + (tid - 320);
            const int tt = dir ? (T_ - 1 - t) : t;
            mupf = mu_arr[mbase + tt];
          } else if (tid < 336) {
            const int t = (sb + 1) * 8 + (tid - 328);
            const int tt = dir ? (T_ - 1 - t) : t;
            rspf = rs_arr[mbase + tt];
          }
        }
        if (sb > 0) {  // bulk h-store of previous group (ring rb^1)
#pragma unroll
          for (int e = 0; e < 2; ++e) {
            const int idx = tid + e * 512;
            const int v = idx >> 7, j = idx & 127;
            const int ts = (sb - 1) * 8 + v;
            const int te = dir ? (T_ - 1 - ts) : ts;
            h0[hbase + (long)te * 256 + dir * 128 + j] = hring[rb ^ 1][v][j];
          }
        }
      }
      // ---- dot phase ----
      v2f hacc[4], xacc[4];
#pragma unroll
      for (int g = 0; g < 4; ++g) { hacc[g] = 0.0f; xacc[g] = 0.0f; }
      const float4* h4v = (const float4*)h4f;
#pragma unroll
      for (int ff = 0; ff < 8; ++ff) {
        const float4 hv = h4v[p * 8 + ((ff + 2 * p) & 7)];
        pkfma(hacc[0], wh[0][ff], hv);
        pkfma(hacc[1], wh[1][ff], hv);
        pkfma(hacc[2], wh[2][ff], hv);
        pkfma(hacc[3], wh[3][ff], hv);
      }
      const float4* xr4 = (const float4*)x_ring[rb][su];
#pragma unroll
      for (int f = 0; f < 3; ++f) {
        const float4 xv = xr4[p * 3 + f];
        pkfma(xacc[0], wi[0][f], xv);
        pkfma(xacc[1], wi[1][f], xv);
        pkfma(xacc[2], wi[2][f], xv);
        pkfma(xacc[3], wi[3][f], xv);
      }
      const float rs = rs_ring[rb][su];
      const float mu = mu_ring[rb][su];
      float pg[4];
#pragma unroll
      for (int g = 0; g < 4; ++g) {
        pg[g] = (hacc[g][0] + hacc[g][1]) + rs * (xacc[g][0] + xacc[g][1]);
        pg[g] += __shfl_xor(pg[g], 1, 64);
        pg[g] += __shfl_xor(pg[g], 2, 64);
        pg[g] += bias[g] - rs * mu * S1[g];
      }
      const float ig = sigf(pg[0]);
      const float fg = sigf(pg[1]);
      const float gg = tanh_fast(pg[2]);
      const float og = sigf(pg[3]);
      c = fg * c + ig * gg;
      const float hv = og * tanh_fast(c);
      if (p == 0) { h4f[u] = hv; hring[rb][su][u] = hv; }
      if (su == 7 && sb + 1 < 125) {  // commit prefetched group to rings rb^1
        if (tid < 320) x_ring[rb ^ 1][lr8][lcol] = xpf;
        else if (tid < 328) mu_ring[rb ^ 1][tid - 320] = mupf;
        else if (tid < 336) rs_ring[rb ^ 1][tid - 328] = rspf;
      }
      __syncthreads();
    }
  }
  // final bulk store (group 124, ring 0)
#pragma unroll
  for (int e = 0; e < 2; ++e) {
    const int idx = tid + e * 512;
    const int v = idx >> 7, j = idx & 127;
    const int ts = 124 * 8 + v;
    const int te = dir ? (T_ - 1 - ts) : ts;
    h0[hbase + (long)te * 256 + dir * 128 + j] = hring[0][v][j];
  }
}

// ---------------- Layer-1 recurrence: quad-mapped, 1 barrier/step, time-chunked ----------------
__global__ __launch_bounds__(512, 1) void rec1_kernel(
    const float* __restrict__ xw_f, const float* __restrict__ xw_b,
    const float* __restrict__ Whh_f, const float* __restrict__ bih_f, const float* __restrict__ bhh_f,
    const float* __restrict__ Whh_b, const float* __restrict__ bih_b, const float* __restrict__ bhh_b,
    unsigned short* __restrict__ h1b, float* __restrict__ state,
    int Tc, int t0f, int t0b, int first) {
  const int tid = threadIdx.x;
  const int u = (tid >> 6) * 16 + ((tid & 63) >> 2);
  const int p = tid & 3;
  const int brow = blockIdx.x & 127;
  const int dir = blockIdx.x >> 7;
  const float* __restrict__ xw = dir ? xw_b : xw_f;
  const float* __restrict__ Whh = dir ? Whh_b : Whh_f;
  const float* __restrict__ bih = dir ? bih_b : bih_f;
  const float* __restrict__ bhh = dir ? bhh_b : bhh_f;
  const int t0 = dir ? t0b : t0f;

  float4 wh[4][8];
#pragma unroll
  for (int g = 0; g < 4; ++g) {
    const float4* wr = (const float4*)(Whh + (g * 128 + u) * 128 + p * 32);
#pragma unroll
    for (int ff = 0; ff < 8; ++ff) wh[g][ff] = wr[(ff + 2 * p) & 7];
  }
  const int myrow = p * 128 + u;
  const float bias_p = bih[myrow] + bhh[myrow];

  __shared__ float h4f[128];
  __shared__ float hring[2][8][128];
  float* sblk = state + (long)blockIdx.x * 256;
  float c = 0.0f;
  if (first) {
    if (tid < 128) h4f[tid] = 0.0f;
  } else {
    if (tid < 128) h4f[tid] = sblk[tid];
    c = sblk[128 + u];  // replicated read per quad
  }
  const long gbase = (long)brow * Tc;
  float xr[8];
#pragma unroll
  for (int v = 0; v < 8; ++v) {
    xr[v] = 0.0f;
    if (v < Tc) {
      const int tr = dir ? (Tc - 1 - v) : v;
      xr[v] = xw[(gbase + tr) * 512 + myrow];
    }
  }
  __syncthreads();

  const int nSB = (Tc + 7) / 8;
  for (int sb = 0; sb < nSB; ++sb) {
    const int rb = sb & 1;
#pragma unroll
    for (int su = 0; su < 8; ++su) {
      const int s = sb * 8 + su;
      if (s >= Tc) break;  // uniform
      if (su == 0 && sb > 0) {  // bulk bf16 store of previous (full) group
#pragma unroll
        for (int e = 0; e < 2; ++e) {
          const int idx = tid + e * 512;
          const int v = idx >> 7, j = idx & 127;
          const int s2 = (sb - 1) * 8 + v;
          const int tt = dir ? (Tc - 1 - s2) : s2;
          h1b[((long)brow * T_ + (t0 + tt)) * 256 + dir * 128 + j] = f2bf(hring[rb ^ 1][v][j]);
        }
      }
      v2f hacc[4];
#pragma unroll
      for (int g = 0; g < 4; ++g) hacc[g] = 0.0f;
      const float4* h4v = (const float4*)h4f;
#pragma unroll
      for (int ff = 0; ff < 8; ++ff) {
        const float4 hv = h4v[p * 8 + ((ff + 2 * p) & 7)];
        pkfma(hacc[0], wh[0][ff], hv);
        pkfma(hacc[1], wh[1][ff], hv);
        pkfma(hacc[2], wh[2][ff], hv);
        pkfma(hacc[3], wh[3][ff], hv);
      }
      const float xin = xr[su] + bias_p;
      float pg[4];
#pragma unroll
      for (int g = 0; g < 4; ++g) {
        pg[g] = hacc[g][0] + hacc[g][1] + ((p == g) ? xin : 0.0f);
        pg[g] += __shfl_xor(pg[g], 1, 64);
        pg[g] += __shfl_xor(pg[g], 2, 64);
      }
      const float ig = sigf(pg[0]);
      const float fg = sigf(pg[1]);
      const float gg = tanh_fast(pg[2]);
      const float og = sigf(pg[3]);
      c = fg * c + ig * gg;
      const float hv = og * tanh_fast(c);
      if (p == 0) { h4f[u] = hv; hring[rb][su][u] = hv; }
      if (su == 7) {  // refill xw for next group (guarded)
#pragma unroll
        for (int v = 0; v < 8; ++v) {
          const int sn = s + 1 + v;
          xr[v] = 0.0f;
          if (sn < Tc) {
            const int tr = dir ? (Tc - 1 - sn) : sn;
            xr[v] = xw[(gbase + tr) * 512 + myrow];
          }
        }
      }
      __syncthreads();
    }
  }
  // final group store
  {
    const int sbL = (Tc - 1) >> 3;
    const int cnt = Tc - sbL * 8;
    const int rbL = sbL & 1;
#pragma unroll
    for (int e = 0; e < 2; ++e) {
      const int idx = tid + e * 512;
      const int v = idx >> 7, j = idx & 127;
      if (v < cnt) {
        const int s2 = sbL * 8 + v;
        const int tt = dir ? (Tc - 1 - s2) : s2;
        h1b[((long)brow * T_ + (t0 + tt)) * 256 + dir * 128 + j] = f2bf(hring[rbL][v][j]);
      }
    }
  }
  if (tid < 128) sblk[tid] = h4f[tid];
  if (p == 0) sblk[128 + u] = c;
}

// ---------------- xw chunk GEMM: tile M=64 x N=128, K-step 32, micro 4x8, pk-fma ----------------
__global__ __launch_bounds__(256, 2) void gemm_xw1(
    const float* __restrict__ h0,
    const float* __restrict__ Wf, const float* __restrict__ Wb,
    float* __restrict__ xwf, float* __restrict__ xwb,
    int Tc, int t0f, int t0b) {
  __shared__ float As[64 * 36];
  __shared__ float Bs[128 * 36];
  __shared__ int rowbase[64];
  const int tid = threadIdx.x;
  const int tx = tid & 15, ty = tid >> 4;
  const int r0 = blockIdx.x * 64;
  const int jt = blockIdx.y;
  const int dir = jt >> 2;
  const int nh = jt & 3;
  const float* __restrict__ W = dir ? Wb : Wf;
  float* __restrict__ out = dir ? xwb : xwf;
  const int jbase = nh * 128;
  const int t0 = dir ? t0b : t0f;

  if (tid < 64) {
    const int r = r0 + tid;
    const int br = r / Tc;
    rowbase[tid] = br * T_ + t0 + (r - br * Tc);
  }

  float4* As4 = (float4*)As;
  float4* Bs4 = (float4*)Bs;
  v2f acc2[4][8];
#pragma unroll
  for (int r = 0; r < 4; ++r)
#pragma unroll
    for (int c2 = 0; c2 < 8; ++c2) acc2[r][c2] = 0.0f;
#pragma unroll 1
  for (int kk = 0; kk < 8; ++kk) {
    __syncthreads();
#pragma unroll
    for (int i = 0; i < 2; ++i) {
      const int q = tid + i * 256;
      const int row = q >> 3, k4 = q & 7;
      As4[row * 9 + k4] = *(const float4*)&h0[(long)rowbase[row] * 256 + kk * 32 + k4 * 4];
    }
#pragma unroll
    for (int i = 0; i < 4; ++i) {
      const int q = tid + i * 256;
      const int row = q >> 3, k4 = q & 7;
      Bs4[row * 9 + k4] = *(const float4*)&W[(long)(jbase + row) * 256 + kk * 32 + k4 * 4];
    }
    __syncthreads();
#pragma unroll 1
    for (int k4 = 0; k4 < 8; ++k4) {
      float4 av[4];
#pragma unroll
      for (int r = 0; r < 4; ++r) av[r] = As4[(ty * 4 + r) * 9 + k4];
#pragma unroll
      for (int c2 = 0; c2 < 8; ++c2) {
        const float4 bv = Bs4[(tx + 16 * c2) * 9 + k4];
#pragma unroll
        for (int r = 0; r < 4; ++r) pkfma(acc2[r][c2], av[r], bv);
      }
    }
  }
#pragma unroll
  for (int r = 0; r < 4; ++r) {
    const long ob = (long)(r0 + ty * 4 + r) * 512 + jbase + tx;
#pragma unroll
    for (int c2 = 0; c2 < 8; ++c2) out[ob + c2 * 16] = acc2[r][c2][0] + acc2[r][c2][1];
  }
}

// ---------------- attention scores ----------------
__global__ __launch_bounds__(256, 2) void score_kernel(
    const unsigned short* __restrict__ h1b, const float* __restrict__ W1,
    const float* __restrict__ b1, const float* __restrict__ w2,
    float* __restrict__ scores) {
  __shared__ float As[64 * 36];
  __shared__ float Bs[128 * 36];
  const int tid = threadIdx.x;
  const int tx = tid & 15, ty = tid >> 4;
  const long r0 = (long)blockIdx.x * 64;

  float4* As4 = (float4*)As;
  float4* Bs4 = (float4*)Bs;
  v2f acc2[4][8];
#pragma unroll
  for (int r = 0; r < 4; ++r)
#pragma unroll
    for (int c2 = 0; c2 < 8; ++c2) acc2[r][c2] = 0.0f;
#pragma unroll 1
  for (int kk = 0; kk < 8; ++kk) {
    __syncthreads();
#pragma unroll
    for (int i = 0; i < 2; ++i) {
      const int q = tid + i * 256;
      const int row = q >> 3, k4 = q & 7;
      const ushort4 uv = *(const ushort4*)&h1b[(r0 + row) * 256 + kk * 32 + k4 * 4];
      As4[row * 9 + k4] = bf4_to_f4(uv);
    }
#pragma unroll
    for (int i = 0; i < 4; ++i) {
      const int q = tid + i * 256;
      const int row = q >> 3, k4 = q & 7;
      Bs4[row * 9 + k4] = *(const float4*)&W1[(long)row * 256 + kk * 32 + k4 * 4];
    }
    __syncthreads();
#pragma unroll 1
    for (int k4 = 0; k4 < 8; ++k4) {
      float4 av[4];
#pragma unroll
      for (int r = 0; r < 4; ++r) av[r] = As4[(ty * 4 + r) * 9 + k4];
#pragma unroll
      for (int c2 = 0; c2 < 8; ++c2) {
        const float4 bv = Bs4[(tx + 16 * c2) * 9 + k4];
#pragma unroll
        for (int r = 0; r < 4; ++r) pkfma(acc2[r][c2], av[r], bv);
      }
    }
  }
#pragma unroll
  for (int r = 0; r < 4; ++r) {
    float s = 0.0f;
#pragma unroll
    for (int c2 = 0; c2 < 8; ++c2) {
      const int col = tx + 16 * c2;
      s += tanh_fast(acc2[r][c2][0] + acc2[r][c2][1] + b1[col]) * w2[col];
    }
#pragma unroll
    for (int m = 1; m < 16; m <<= 1) s += __shfl_xor(s, m, 16);
    if (tx == 0) scores[r0 + ty * 4 + r] = s;
  }
}

// ---------------- softmax over T + ctx + MLP head ----------------
__global__ __launch_bounds__(256, 2) void head_kernel(
    const float* __restrict__ scores, const unsigned short* __restrict__ h1b,
    const float* __restrict__ fW1, const float* __restrict__ fb1,
    const float* __restrict__ fW2, const float* __restrict__ fb2,
    float* __restrict__ outp) {
  const int b = blockIdx.x, tid = threadIdx.x;
  __shared__ float wls[1000];
  __shared__ float red[8];
  __shared__ __align__(16) float ctx[256];
  __shared__ __align__(16) float hid[128];

  float sv[4];
  float mx = -1e30f;
#pragma unroll
  for (int i = 0; i < 4; ++i) {
    const int t = tid + i * 256;
    sv[i] = (t < 1000) ? scores[b * 1000 + t] : -1e30f;
    mx = fmaxf(mx, sv[i]);
  }
  for (int m = 32; m; m >>= 1) mx = fmaxf(mx, __shfl_xor(mx, m, 64));
  if ((tid & 63) == 0) red[tid >> 6] = mx;
  __syncthreads();
  mx = fmaxf(fmaxf(red[0], red[1]), fmaxf(red[2], red[3]));
  float se = 0.0f;
#pragma unroll
  for (int i = 0; i < 4; ++i) {
    const int t = tid + i * 256;
    if (t < 1000) {
      const float e = __expf(sv[i] - mx);
      wls[t] = e;
      se += e;
    }
  }
  for (int m = 32; m; m >>= 1) se += __shfl_xor(se, m, 64);
  if ((tid & 63) == 0) red[4 + (tid >> 6)] = se;
  __syncthreads();
  const float rinv = 1.0f / (red[4] + red[5] + red[6] + red[7]);

  float a = 0.0f;
  const unsigned short* hb = h1b + (long)b * T_ * 256 + tid;
  for (int t = 0; t < T_; ++t) a = fmaf(wls[t], bf2f(hb[t * 256]), a);
  ctx[tid] = a * rinv;
  __syncthreads();
  if (tid < 128) {
    float s = fb1[tid];
    const float4* wr = (const float4*)&fW1[tid * 256];
    const float4* cc = (const float4*)ctx;
#pragma unroll
    for (int f = 0; f < 64; ++f) s += dot4(wr[f], cc[f]);
    hid[tid] = fmaxf(s, 0.0f);
  }
  __syncthreads();
  if (tid < 8) {
    float s = fb2[tid];
    const float4* wr = (const float4*)&fW2[tid * 128];
    const float4* hh = (const float4*)hid;
#pragma unroll
    for (int f = 0; f < 32; ++f) s += dot4(wr[f], hh[f]);
    outp[b * 8 + tid] = s;
  }
}

extern "C" void kernel_launch(void* const* d_in, const int* in_sizes, int n_in,
                              void* d_out, int out_size, void* d_ws, size_t ws_size,
                              hipStream_t stream) {
  (void)in_sizes; (void)n_in; (void)out_size;
  const float* x       = (const float*)d_in[0];
  const float* ln_g    = (const float*)d_in[1];
  const float* ln_b    = (const float*)d_in[2];
  const float* Wih_f0  = (const float*)d_in[3];
  const float* Whh_f0  = (const float*)d_in[4];
  const float* bih_f0  = (const float*)d_in[5];
  const float* bhh_f0  = (const float*)d_in[6];
  const float* Wih_b0  = (const float*)d_in[7];
  const float* Whh_b0  = (const float*)d_in[8];
  const float* bih_b0  = (const float*)d_in[9];
  const float* bhh_b0  = (const float*)d_in[10];
  const float* Wih_f1  = (const float*)d_in[11];
  const float* Whh_f1  = (const float*)d_in[12];
  const float* bih_f1  = (const float*)d_in[13];
  const float* bhh_f1  = (const float*)d_in[14];
  const float* Wih_b1  = (const float*)d_in[15];
  const float* Whh_b1  = (const float*)d_in[16];
  const float* bih_b1  = (const float*)d_in[17];
  const float* bhh_b1  = (const float*)d_in[18];
  const float* attn_W1 = (const float*)d_in[19];
  const float* attn_b1 = (const float*)d_in[20];
  const float* attn_w2 = (const float*)d_in[21];
  const float* fc_W1   = (const float*)d_in[22];
  const float* fc_b1   = (const float*)d_in[23];
  const float* fc_W2   = (const float*)d_in[24];
  const float* fc_b2   = (const float*)d_in[25];

  char* base = (char*)d_ws;
  size_t off = 0;
  auto alloc = [&](size_t bytes) {
    char* ptr = base + off;
    off += (bytes + 255) & ~(size_t)255;
    return ptr;
  };
  float*          h0    = (float*)alloc(32768000ull * 4);          // 131.1 MB
  unsigned short* h1b   = (unsigned short*)alloc(32768000ull * 2); //  65.5 MB
  float*          state = (float*)alloc(65536ull * 4);
  float*          scor  = (float*)alloc(128000ull * 4);
  float*          mu_a  = (float*)alloc(128000ull * 4);
  float*          rs_a  = (float*)alloc(128000ull * 4);

  const size_t rem = (ws_size > off) ? (ws_size - off) : 0;
  static const int cands[16] = {1000, 500, 250, 200, 125, 100, 50, 40, 25, 20, 10, 8, 5, 4, 2, 1};
  int Tc = 0;
  for (int ci = 0; ci < 16; ++ci) {
    if (524288ull * (size_t)cands[ci] <= rem) { Tc = cands[ci]; break; }
  }
  if (Tc == 0) {
    bail_kernel<<<dim3(1), dim3(256), 0, stream>>>((float*)d_out, 1024);
    return;
  }
  float* xwf = (float*)(base + off);
  float* xwb = xwf + 65536L * Tc;

  ln_stats_kernel<<<dim3(32000), dim3(256), 0, stream>>>(x, mu_a, rs_a);
  rec0_kernel<<<dim3(256), dim3(512), 0, stream>>>(x, mu_a, rs_a, ln_g, ln_b,
                                                   Wih_f0, Whh_f0, bih_f0, bhh_f0,
                                                   Wih_b0, Whh_b0, bih_b0, bhh_b0, h0);
  const int nch = T_ / Tc;
  for (int ch = 0; ch < nch; ++ch) {
    const int t0f = ch * Tc;
    const int t0b = T_ - (ch + 1) * Tc;
    gemm_xw1<<<dim3(2 * Tc, 8), dim3(256), 0, stream>>>(h0, Wih_f1, Wih_b1, xwf, xwb, Tc, t0f, t0b);
    rec1_kernel<<<dim3(256), dim3(512), 0, stream>>>(xwf, xwb, Whh_f1, bih_f1, bhh_f1,
                                                     Whh_b1, bih_b1, bhh_b1, h1b, state,
                                                     Tc, t0f, t0b, (ch == 0) ? 1 : 0);
  }
  score_kernel<<<dim3(2000), dim3(256), 0, stream>>>(h1b, attn_W1, attn_b1, attn_w2, scor);
  head_kernel<<<dim3(128), dim3(256), 0, stream>>>(scor, h1b, fc_W1, fc_b1, fc_W2, fc_b2,
                                                   (float*)d_out);
}